// Round 1
// baseline (529.399 us; speedup 1.0000x reference)
//
#include <hip/hip_runtime.h>

// GCN layer: out = ReLU( D^-1/2 (A+I) D^-1/2 X W + b ), N=8192, IN=OUT=256.
// fp32 I/O; bf16 internally for MFMA.
//   deg = rowsum(adj); s_i = rsqrt(deg_i+1); Z = X@W;
//   out[i,n] = relu( s_i * sum_j adj[i,j]*s_j*Z[j,n] + s_i^2*Z[i,n] + b[n] )
//
// v2 structure: k_deg reads fp32 adj ONCE and emits both split-K partial rowsums
// (degree4[4][8192]) and adjb — bf16 adj pre-laid-out in k_main's GLDS stream
// order. k_main then stages A with a single global_load_lds (no fp32 load, no
// f2b, no ds_write in the hot loop) and reads only 128 MB (likely LLC-warm).
//
// adjb unit (16B = 8 bf16 along k) linear index:
//   ((mb*4 + sk)*64 + i)*256 + q*64 + r
//   (mb = row/64, sk = k/2048, i = (k%2048)/32 tile, q = (k%32)/8, r = row%64)
// k_main LDS A image: unit (q,r) at byte q*1040 + r*16  (65-unit rows; the
// GLDS stream per tile is 4 waves x 64 contiguous units -> per-wave base w*1040).
// Zsb (bf16 s_k*Z[k][n]) 16B-unit idx = ktg*2048 + kc*256 + n (unchanged).

typedef __attribute__((ext_vector_type(8))) short short8;
typedef __attribute__((ext_vector_type(4))) float floatx4;

#define GLDS16(g, l) __builtin_amdgcn_global_load_lds(\
    (const __attribute__((address_space(1))) void*)(g), \
    (__attribute__((address_space(3))) void*)(l), 16, 0, 0)

// fp32 -> bf16 round-to-nearest-even
__device__ __forceinline__ unsigned short f2b(float f) {
  unsigned int x = __builtin_bit_cast(unsigned int, f);
  unsigned int r = (x + 0x7fffu + ((x >> 16) & 1u)) >> 16;
  return (unsigned short)r;
}

// ---- kernel 1: adjb (bf16, GLDS-stream layout) + split-K partial rowsums ----
// 512 blocks x 512 thr (2/CU). Block (mb = b>>2, sk = b&3): rows m0..m0+64,
// k-range sk*2048..+2048. Wave w: tiles i in [8w, 8w+8); lane l = row m0+l.
// Reads: per lane per i one full 128B line (8 float4, fully consumed).
// Writes: per (i,q) 64 lanes x 16B contiguous = 1KB. Panel is block-local, so
// no cross-XCD partial-line writes.
__global__ __launch_bounds__(512) void k_deg(
    const float* __restrict__ adj, unsigned short* __restrict__ adjb,
    float* __restrict__ degree4) {
  __shared__ float part[8][64];
  const int t = threadIdx.x, l = t & 63, w = t >> 6;
  const int mb = blockIdx.x >> 2, sk = blockIdx.x & 3;
  const int m0 = mb * 64;
  const float* src = adj + (size_t)(m0 + l) * 8192 + sk * 2048;
  // short offset of unit (i,q,r=l): ((mb*4+sk)*16384 + (i*4+q)*64 + l)*8
  unsigned short* dstBase = adjb + ((size_t)(mb * 4 + sk) * 16384 + l) * 8;
  float rs = 0.f;
  for (int i = w * 8; i < w * 8 + 8; ++i) {
    const float* s = src + i * 32;
#pragma unroll
    for (int q = 0; q < 4; ++q) {
      float4 v0 = *(const float4*)(s + q * 8);
      float4 v1 = *(const float4*)(s + q * 8 + 4);
      short8 u;
      u[0] = f2b(v0.x); u[1] = f2b(v0.y); u[2] = f2b(v0.z); u[3] = f2b(v0.w);
      u[4] = f2b(v1.x); u[5] = f2b(v1.y); u[6] = f2b(v1.z); u[7] = f2b(v1.w);
      *(short8*)(dstBase + (size_t)(i * 4 + q) * 512) = u;
      rs += ((v0.x + v0.y) + (v0.z + v0.w)) + ((v1.x + v1.y) + (v1.z + v1.w));
    }
  }
  part[w][l] = rs;
  __syncthreads();
  if (t < 64) {
    float s = 0.f;
#pragma unroll
    for (int ww = 0; ww < 8; ++ww) s += part[ww][t];
    degree4[sk * 8192 + m0 + t] = s;
  }
}

// ---- kernel 2: Z = X@W (VALU fp32); Zd = s^2 Z + b; Zsb swizzled; sinv ------
// 512 blocks x 256 thr (2/CU, 2 waves/SIMD). Wave w: rows m0+4w..+4; lane l:
// cols 4l..4l+4. Sums the 4 degree partials; writes sinv for k_fin.
__global__ __launch_bounds__(256) void k_xw(
    const float* __restrict__ X, const float* __restrict__ W,
    const float* __restrict__ bias, const float* __restrict__ degree4,
    float* __restrict__ Zd, unsigned short* __restrict__ Zsb,
    float* __restrict__ sinv) {
  __shared__ unsigned short ldsT[256 * 20];   // [n][mm], stride 20 shorts
  const int t = threadIdx.x, l = t & 63, w = t >> 6;
  const int m0 = blockIdx.x * 16;
  const int r0 = w * 4;
  const int n0 = l * 4;
  const float* Xp = X + (size_t)(m0 + r0) * 256;
  float acc[4][4] = {};
#pragma unroll 2
  for (int k = 0; k < 256; k += 4) {
    float4 wv[4];
#pragma unroll
    for (int j = 0; j < 4; ++j) wv[j] = *(const float4*)(W + (size_t)(k + j) * 256 + n0);
#pragma unroll
    for (int r = 0; r < 4; ++r) {
      float4 xv = *(const float4*)(Xp + r * 256 + k);   // wave-uniform broadcast
      const float xs[4] = {xv.x, xv.y, xv.z, xv.w};
#pragma unroll
      for (int j = 0; j < 4; ++j) {
        acc[r][0] += xs[j] * wv[j].x;
        acc[r][1] += xs[j] * wv[j].y;
        acc[r][2] += xs[j] * wv[j].z;
        acc[r][3] += xs[j] * wv[j].w;
      }
    }
  }
  const float4 bv = *(const float4*)(bias + n0);
#pragma unroll
  for (int r = 0; r < 4; ++r) {
    const int row = m0 + r0 + r;
    const float deg = degree4[row] + degree4[8192 + row]
                    + degree4[16384 + row] + degree4[24576 + row];
    const float sr = rsqrtf(deg + 1.0f);
    if (l == 0) sinv[row] = sr;
    float4 zd;
    zd.x = sr * sr * acc[r][0] + bv.x;
    zd.y = sr * sr * acc[r][1] + bv.y;
    zd.z = sr * sr * acc[r][2] + bv.z;
    zd.w = sr * sr * acc[r][3] + bv.w;
    *(float4*)(Zd + (size_t)row * 256 + n0) = zd;
#pragma unroll
    for (int n = 0; n < 4; ++n)
      ldsT[(size_t)(n0 + n) * 20 + (r0 + r)] = f2b(sr * acc[r][n]);
  }
  __syncthreads();
  const int kt = m0 >> 6, kcb = (m0 >> 3) & 7;   // 16 rows = 2 kc groups
#pragma unroll
  for (int c = 0; c < 2; ++c) {
    const unsigned short* p = ldsT + (size_t)t * 20 + c * 8;
    short8 vv;
#pragma unroll
    for (int j = 0; j < 8; ++j) vv[j] = p[j];
    *(short8*)(Zsb + ((size_t)kt * 2048 + (kcb + c) * 256 + t) * 8) = vv;
  }
}

// ---- kernel 3: P[sk] = adjb @ Zsb, split-K=4 --------------------------------
// 512 blocks x 512 thr (2/CU, 16 waves/CU). b: bm = b>>2, sk = b&3.
// BM=64, BN=256, BK=32. Hot loop per thread: <=3 GLDS16 + 6 ds_read_b128 +
// 8 MFMA + barrier — no fp32 A path, no f2b, no ds_write.
__global__ __launch_bounds__(512) void k_main(
    const unsigned short* __restrict__ adjb, const unsigned short* __restrict__ Zsb,
    float* __restrict__ P) {
  // per stage: A = 4*1040 = 4160 (pad to 4224, 16-al), B = 16384 -> 20608
  __shared__ __align__(16) char lds[2][20608];
  const int t = threadIdx.x, l = t & 63, w = t >> 6;
  const int quad = l >> 4, nl = l & 15;
  const int bm = blockIdx.x >> 2, sk = blockIdx.x & 3;
  const int m0 = bm * 64;
  const int wm = w & 1, wn = w >> 1;           // 2x4 wave grid, 32x64 per wave
  const unsigned short* aBase = adjb + (size_t)(bm * 4 + sk) * 131072; // 16384 units * 8
  const unsigned short* bBase = Zsb + (size_t)sk * 524288;             // 65536 units * 8
  floatx4 acc[2][4] = {};

  // prologue: stage tile 0 (A: waves 0-3, one GLDS each; B: 2 GLDS/thread)
  if (t < 256)
    GLDS16(aBase + (size_t)t * 8, lds[0] + (t >> 6) * 1040 + (t & 63) * 16);
#pragma unroll
  for (int q = 0; q < 2; ++q) {
    const int sl = q * 512 + t;
    GLDS16(bBase + (size_t)sl * 8, lds[0] + 4224 + sl * 16);
  }
  __syncthreads();

  for (int i = 0; i < 64; ++i) {
    const int cur = i & 1, nxt = cur ^ 1;
    const int ib = i < 63 ? i + 1 : 63;        // tile to stage (clamped, redundant ok)
    if (t < 256)
      GLDS16(aBase + ((size_t)ib * 256 + t) * 8,
             lds[nxt] + (t >> 6) * 1040 + (t & 63) * 16);
#pragma unroll
    for (int q = 0; q < 2; ++q) {
      const int sl = q * 512 + t;
      GLDS16(bBase + ((size_t)ib * 1024 + sl) * 8, lds[nxt] + 4224 + sl * 16);
    }
    // compute tile i
    const char* rA = lds[cur];
    const char* rB = lds[cur] + 4224;
    short8 af[2], bf[4];
    af[0] = *(const short8*)(rA + quad * 1040 + (wm * 32 + nl) * 16);
    af[1] = *(const short8*)(rA + quad * 1040 + (wm * 32 + 16 + nl) * 16);
#pragma unroll
    for (int nf = 0; nf < 4; ++nf) {
      const int col = wn * 64 + nf * 16 + nl;
      bf[nf] = *(const short8*)(rB + ((size_t)quad * 256 + col) * 16);
    }
#pragma unroll
    for (int mi = 0; mi < 2; ++mi)
#pragma unroll
      for (int nf = 0; nf < 4; ++nf)
        acc[mi][nf] = __builtin_amdgcn_mfma_f32_16x16x32_bf16(af[mi], bf[nf], acc[mi][nf], 0, 0, 0);
    __syncthreads();
  }

  float* Pk = P + (size_t)sk * 8192 * 256;
#pragma unroll
  for (int mi = 0; mi < 2; ++mi)
#pragma unroll
    for (int nf = 0; nf < 4; ++nf)
#pragma unroll
      for (int r = 0; r < 4; ++r) {
        const int row = m0 + wm * 32 + mi * 16 + quad * 4 + r;
        const int col = wn * 64 + nf * 16 + nl;
        Pk[(size_t)row * 256 + col] = acc[mi][nf][r];
      }
}

// ---- kernel 4: out = relu( s_i*(P0+P1+P2+P3) + Zd ) ------------------------
__global__ __launch_bounds__(256) void k_fin(
    const float* __restrict__ P, const float* __restrict__ Zd,
    const float* __restrict__ sinv, float* __restrict__ out) {
  const int i = blockIdx.x * 256 + threadIdx.x;     // float4 index
  const int row = i >> 6;
  const float sr = sinv[row];
  const size_t stride = (size_t)8192 * 256;
  float4 p0 = *(const float4*)(P + (size_t)i * 4);
  float4 p1 = *(const float4*)(P + stride + (size_t)i * 4);
  float4 p2 = *(const float4*)(P + 2 * stride + (size_t)i * 4);
  float4 p3 = *(const float4*)(P + 3 * stride + (size_t)i * 4);
  const float4 zd = *(const float4*)(Zd + (size_t)i * 4);
  float4 v;
  v.x = sr * ((p0.x + p1.x) + (p2.x + p3.x)) + zd.x;
  v.y = sr * ((p0.y + p1.y) + (p2.y + p3.y)) + zd.y;
  v.z = sr * ((p0.z + p1.z) + (p2.z + p3.z)) + zd.z;
  v.w = sr * ((p0.w + p1.w) + (p2.w + p3.w)) + zd.w;
  v.x = v.x > 0.f ? v.x : 0.f;
  v.y = v.y > 0.f ? v.y : 0.f;
  v.z = v.z > 0.f ? v.z : 0.f;
  v.w = v.w > 0.f ? v.w : 0.f;
  *(float4*)(out + (size_t)i * 4) = v;
}

// ============================================================================
extern "C" void kernel_launch(void* const* d_in, const int* in_sizes, int n_in,
                              void* d_out, int out_size, void* d_ws, size_t ws_size,
                              hipStream_t stream) {
  const float* X    = (const float*)d_in[0];   // [8192][256]
  const float* adj  = (const float*)d_in[1];   // [8192][8192]
  const float* W    = (const float*)d_in[2];   // [256][256] ([in][out])
  const float* bias = (const float*)d_in[3];   // [256]
  float* out = (float*)d_out;                  // [8192][256]
  char* ws = (char*)d_ws;

  float* degree4       = (float*)(ws);                      // 128 KB (4 x 8192)
  float* sinv          = (float*)(ws + (256 << 10));        // 32 KB
  float* Zd            = (float*)(ws + (1 << 20));          // 8 MB
  unsigned short* Zsb  = (unsigned short*)(ws + (9 << 20)); // 4 MB
  float* P             = (float*)(ws + (13 << 20));         // 32 MB (4 x 8 MB)
  unsigned short* adjb = (unsigned short*)(ws + (45 << 20));// 128 MB  -> total 173 MB

  hipLaunchKernelGGL(k_deg,  dim3(512),  dim3(512), 0, stream, adj, adjb, degree4);
  hipLaunchKernelGGL(k_xw,   dim3(512),  dim3(256), 0, stream, X, W, bias, degree4, Zd, Zsb, sinv);
  hipLaunchKernelGGL(k_main, dim3(512),  dim3(512), 0, stream, adjb, Zsb, P);
  hipLaunchKernelGGL(k_fin,  dim3(2048), dim3(256), 0, stream, P, Zd, sinv, out);
}

// Round 2
// 525.244 us; speedup vs baseline: 1.0079x; 1.0079x over previous
//
#include <hip/hip_runtime.h>

// GCN layer: out = ReLU( D^-1/2 (A+I) D^-1/2 X W + b ), N=8192, IN=OUT=256.
// fp32 I/O; bf16 internally for MFMA.
//   deg = rowsum(adj); s_i = rsqrt(deg_i+1); Z = X@W;
//   out[i,n] = relu( s_i * sum_j adj[i,j]*s_j*Z[j,n] + s_i^2*Z[i,n] + b[n] )
//
// v3: k_deg reads adj coalesced (LDS transpose) and emits adjb in k_main's
// stream order + 8 degree partials. k_main: BM=128,BN=128,BK=64, 32 iters,
// 32 MFMA/thread/iter, 2 blocks/CU, padded LDS stripes (2064B).
//
// adjb unit (16B = 8 bf16 along k) linear index:
//   (mb2*4 + sk)*32768 + i*1024 + q*128 + r
//   (mb2=row/128, sk=k/2048, i=(k%2048)/64, q=(k%64)/8, r=row%128)
// k_main LDS A image: unit (q,r) at byte q*2064 + r*16 (stripe pad -> +4 banks)
// B image: unit (q,col) at byte 16512 + q*2064 + col*16, col = n - bn*128.
// Zsb (bf16 s_k*Z[k][n]) 16B-unit idx = kt*2048 + kc*256 + n (unchanged).

typedef __attribute__((ext_vector_type(8))) short short8;
typedef __attribute__((ext_vector_type(4))) float floatx4;

#define GLDS16(g, l) __builtin_amdgcn_global_load_lds(\
    (const __attribute__((address_space(1))) void*)(g), \
    (__attribute__((address_space(3))) void*)(l), 16, 0, 0)

// fp32 -> bf16 round-to-nearest-even
__device__ __forceinline__ unsigned short f2b(float f) {
  unsigned int x = __builtin_bit_cast(unsigned int, f);
  unsigned int r = (x + 0x7fffu + ((x >> 16) & 1u)) >> 16;
  return (unsigned short)r;
}

// ---- kernel 1: adjb (bf16, k_main stream order) + 8 partial rowsums --------
// 512 blocks x 512 thr (2/CU). Block (mb2 = b>>3, sk = (b>>1)&3, h = b&1):
// rows mb2*128..+128, k-range sk*2048 + h*1024 ..+1024 (16 tiles, 4 slabs).
// Read: 16 rowgroups x 32 lanes; lane c reads 8 consecutive floats (2 float4,
// 1KB contiguous per group-instr pair). Transpose via 64KB LDS slab with XOR
// swizzle (slot = row ^ (stripe&7)); write-out 8KB contiguous per instr.
__global__ __launch_bounds__(512) void k_deg(
    const float* __restrict__ adj, unsigned short* __restrict__ adjb,
    float* __restrict__ degree8) {
  __shared__ __align__(16) char xlds[65536];
  const int t = threadIdx.x, g = t >> 5, c = t & 31;
  const int mb2 = blockIdx.x >> 3, sk = (blockIdx.x >> 1) & 3, h = blockIdx.x & 1;
  const float* src = adj + (size_t)mb2 * 128 * 8192 + sk * 2048 + h * 1024;
  unsigned short* dstP = adjb
      + ((size_t)(mb2 * 4 + sk) * 32768 + (size_t)h * 16384) * 8;
  float rs[8] = {};
#pragma unroll
  for (int s = 0; s < 4; ++s) {
#pragma unroll
    for (int rr = 0; rr < 8; ++rr) {
      const int row = rr * 16 + g;
      const float* p = src + (size_t)row * 8192 + s * 256 + c * 8;
      float4 v0 = *(const float4*)(p);
      float4 v1 = *(const float4*)(p + 4);
      rs[rr] += ((v0.x + v0.y) + (v0.z + v0.w)) + ((v1.x + v1.y) + (v1.z + v1.w));
      short8 u;
      u[0] = f2b(v0.x); u[1] = f2b(v0.y); u[2] = f2b(v0.z); u[3] = f2b(v0.w);
      u[4] = f2b(v1.x); u[5] = f2b(v1.y); u[6] = f2b(v1.z); u[7] = f2b(v1.w);
      // stripe = (c>>3)*8 + (c&7) = c ; slot = row ^ (c&7)
      *(short8*)(xlds + c * 2048 + ((row ^ (c & 7)) * 16)) = u;
    }
    __syncthreads();
    unsigned short* dst = dstP + (size_t)s * 4096 * 8;
#pragma unroll
    for (int j = 0; j < 8; ++j) {
      const int lu = j * 512 + t;
      const int U = lu >> 7, R = lu & 127;
      short8 u = *(const short8*)(xlds + U * 2048 + ((R ^ (U & 7)) * 16));
      *(short8*)(dst + (size_t)lu * 8) = u;
    }
    __syncthreads();
  }
#pragma unroll
  for (int rr = 0; rr < 8; ++rr) {
#pragma unroll
    for (int o = 16; o > 0; o >>= 1) rs[rr] += __shfl_down(rs[rr], o, 32);
  }
  if (c == 0) {
    float* dp = degree8 + (size_t)(sk * 2 + h) * 8192 + mb2 * 128;
#pragma unroll
    for (int rr = 0; rr < 8; ++rr) dp[rr * 16 + g] = rs[rr];
  }
}

// ---- kernel 2: Z = X@W (VALU fp32); Zd = s^2 Z + b; Zsb swizzled; sinv ------
// 512 blocks x 256 thr. Wave w: rows m0+4w..+4; lane l: cols 4l..4l+4.
__global__ __launch_bounds__(256) void k_xw(
    const float* __restrict__ X, const float* __restrict__ W,
    const float* __restrict__ bias, const float* __restrict__ degree8,
    float* __restrict__ Zd, unsigned short* __restrict__ Zsb,
    float* __restrict__ sinv) {
  __shared__ unsigned short ldsT[256 * 20];   // [n][mm], stride 20 shorts
  const int t = threadIdx.x, l = t & 63, w = t >> 6;
  const int m0 = blockIdx.x * 16;
  const int r0 = w * 4;
  const int n0 = l * 4;
  const float* Xp = X + (size_t)(m0 + r0) * 256;
  float acc[4][4] = {};
#pragma unroll 2
  for (int k = 0; k < 256; k += 4) {
    float4 wv[4];
#pragma unroll
    for (int j = 0; j < 4; ++j) wv[j] = *(const float4*)(W + (size_t)(k + j) * 256 + n0);
#pragma unroll
    for (int r = 0; r < 4; ++r) {
      float4 xv = *(const float4*)(Xp + r * 256 + k);   // wave-uniform broadcast
      const float xs[4] = {xv.x, xv.y, xv.z, xv.w};
#pragma unroll
      for (int j = 0; j < 4; ++j) {
        acc[r][0] += xs[j] * wv[j].x;
        acc[r][1] += xs[j] * wv[j].y;
        acc[r][2] += xs[j] * wv[j].z;
        acc[r][3] += xs[j] * wv[j].w;
      }
    }
  }
  const float4 bv = *(const float4*)(bias + n0);
#pragma unroll
  for (int r = 0; r < 4; ++r) {
    const int row = m0 + r0 + r;
    float deg = 0.f;
#pragma unroll
    for (int p = 0; p < 8; ++p) deg += degree8[(size_t)p * 8192 + row];
    const float sr = rsqrtf(deg + 1.0f);
    if (l == 0) sinv[row] = sr;
    float4 zd;
    zd.x = sr * sr * acc[r][0] + bv.x;
    zd.y = sr * sr * acc[r][1] + bv.y;
    zd.z = sr * sr * acc[r][2] + bv.z;
    zd.w = sr * sr * acc[r][3] + bv.w;
    *(float4*)(Zd + (size_t)row * 256 + n0) = zd;
#pragma unroll
    for (int n = 0; n < 4; ++n)
      ldsT[(size_t)(n0 + n) * 20 + (r0 + r)] = f2b(sr * acc[r][n]);
  }
  __syncthreads();
  const int kt = m0 >> 6, kcb = (m0 >> 3) & 7;   // 16 rows = 2 kc groups
#pragma unroll
  for (int c = 0; c < 2; ++c) {
    const unsigned short* p = ldsT + (size_t)t * 20 + c * 8;
    short8 vv;
#pragma unroll
    for (int j = 0; j < 8; ++j) vv[j] = p[j];
    *(short8*)(Zsb + ((size_t)kt * 2048 + (kcb + c) * 256 + t) * 8) = vv;
  }
}

// ---- kernel 3: P[sk] = adjb @ Zsb --------------------------------------------
// 512 blocks x 256 thr (2/CU). b: bm2 = b>>3, bn = (b>>2)&1, sk = b&3.
// BM=128, BN=128, BK=64, 32 iters. Per thread-iter: 8 GLDS16 + 16 ds_read_b128
// + 32 MFMA + 1 barrier. LDS 2 x 33024 = 66KB -> 2 blocks/CU (132KB).
__global__ __launch_bounds__(256, 2) void k_main(
    const unsigned short* __restrict__ adjb, const unsigned short* __restrict__ Zsb,
    float* __restrict__ P) {
  __shared__ __align__(16) char lds[2][33024];   // A: 8x2064, B: 8x2064 @16512
  const int t = threadIdx.x, l = t & 63, w = t >> 6;
  const int quad = l >> 4, nl = l & 15;
  const int bm2 = blockIdx.x >> 3, bn = (blockIdx.x >> 2) & 1, sk = blockIdx.x & 3;
  const int wm = w & 1, wn = w >> 1;             // 2x2 wave grid, 64x64 per wave
  const unsigned short* aBase = adjb + (size_t)(bm2 * 4 + sk) * 32768 * 8;
  const unsigned short* bBase = Zsb + ((size_t)sk * 32 * 2048 + bn * 128) * 8;
  floatx4 acc[4][4] = {};

  // prologue: stage tile 0
#pragma unroll
  for (int p = 0; p < 4; ++p) {
    const int j = p * 256 + t;
    const int q = j >> 7, rr = j & 127;          // q wave-uniform; rr = (w&1)*64+l
    GLDS16(aBase + (size_t)j * 8, lds[0] + q * 2064 + rr * 16);
    GLDS16(bBase + (size_t)(q * 256 + rr) * 8, lds[0] + 16512 + q * 2064 + rr * 16);
  }
  __syncthreads();

  for (int i = 0; i < 32; ++i) {
    const int cur = i & 1, nxt = cur ^ 1;
    const int ib = i < 31 ? i + 1 : 31;          // clamped redundant restage ok
#pragma unroll
    for (int p = 0; p < 4; ++p) {
      const int j = p * 256 + t;
      const int q = j >> 7, rr = j & 127;
      GLDS16(aBase + ((size_t)ib * 1024 + j) * 8, lds[nxt] + q * 2064 + rr * 16);
      GLDS16(bBase + ((size_t)ib * 2048 + q * 256 + rr) * 8,
             lds[nxt] + 16512 + q * 2064 + rr * 16);
    }
    const char* rA = lds[cur];
    const char* rB = lds[cur] + 16512;
#pragma unroll
    for (int kk = 0; kk < 2; ++kk) {
      const int qq = kk * 4 + quad;
      short8 af[4], bf[4];
#pragma unroll
      for (int mi = 0; mi < 4; ++mi)
        af[mi] = *(const short8*)(rA + qq * 2064 + (wm * 64 + mi * 16 + nl) * 16);
#pragma unroll
      for (int nf = 0; nf < 4; ++nf)
        bf[nf] = *(const short8*)(rB + qq * 2064 + (wn * 64 + nf * 16 + nl) * 16);
#pragma unroll
      for (int mi = 0; mi < 4; ++mi)
#pragma unroll
        for (int nf = 0; nf < 4; ++nf)
          acc[mi][nf] = __builtin_amdgcn_mfma_f32_16x16x32_bf16(af[mi], bf[nf], acc[mi][nf], 0, 0, 0);
    }
    __syncthreads();
  }

  float* Pk = P + (size_t)sk * 8192 * 256 + (size_t)bn * 128;
#pragma unroll
  for (int mi = 0; mi < 4; ++mi)
#pragma unroll
    for (int nf = 0; nf < 4; ++nf)
#pragma unroll
      for (int r = 0; r < 4; ++r) {
        const int row = bm2 * 128 + wm * 64 + mi * 16 + quad * 4 + r;
        const int col = wn * 64 + nf * 16 + nl;
        Pk[(size_t)row * 256 + col] = acc[mi][nf][r];
      }
}

// ---- kernel 4: out = relu( s_i*(P0+P1+P2+P3) + Zd ) ------------------------
__global__ __launch_bounds__(256) void k_fin(
    const float* __restrict__ P, const float* __restrict__ Zd,
    const float* __restrict__ sinv, float* __restrict__ out) {
  const int i = blockIdx.x * 256 + threadIdx.x;     // float4 index
  const int row = i >> 6;
  const float sr = sinv[row];
  const size_t stride = (size_t)8192 * 256;
  float4 p0 = *(const float4*)(P + (size_t)i * 4);
  float4 p1 = *(const float4*)(P + stride + (size_t)i * 4);
  float4 p2 = *(const float4*)(P + 2 * stride + (size_t)i * 4);
  float4 p3 = *(const float4*)(P + 3 * stride + (size_t)i * 4);
  const float4 zd = *(const float4*)(Zd + (size_t)i * 4);
  float4 v;
  v.x = sr * ((p0.x + p1.x) + (p2.x + p3.x)) + zd.x;
  v.y = sr * ((p0.y + p1.y) + (p2.y + p3.y)) + zd.y;
  v.z = sr * ((p0.z + p1.z) + (p2.z + p3.z)) + zd.z;
  v.w = sr * ((p0.w + p1.w) + (p2.w + p3.w)) + zd.w;
  v.x = v.x > 0.f ? v.x : 0.f;
  v.y = v.y > 0.f ? v.y : 0.f;
  v.z = v.z > 0.f ? v.z : 0.f;
  v.w = v.w > 0.f ? v.w : 0.f;
  *(float4*)(out + (size_t)i * 4) = v;
}

// ============================================================================
extern "C" void kernel_launch(void* const* d_in, const int* in_sizes, int n_in,
                              void* d_out, int out_size, void* d_ws, size_t ws_size,
                              hipStream_t stream) {
  const float* X    = (const float*)d_in[0];   // [8192][256]
  const float* adj  = (const float*)d_in[1];   // [8192][8192]
  const float* W    = (const float*)d_in[2];   // [256][256] ([in][out])
  const float* bias = (const float*)d_in[3];   // [256]
  float* out = (float*)d_out;                  // [8192][256]
  char* ws = (char*)d_ws;

  float* degree8       = (float*)(ws);                      // 256 KB (8 x 8192)
  float* sinv          = (float*)(ws + (512 << 10));        // 32 KB
  float* Zd            = (float*)(ws + (1 << 20));          // 8 MB
  unsigned short* Zsb  = (unsigned short*)(ws + (9 << 20)); // 4 MB
  float* P             = (float*)(ws + (13 << 20));         // 32 MB (4 x 8 MB)
  unsigned short* adjb = (unsigned short*)(ws + (45 << 20));// 128 MB -> total 173 MB

  hipLaunchKernelGGL(k_deg,  dim3(512),  dim3(512), 0, stream, adj, adjb, degree8);
  hipLaunchKernelGGL(k_xw,   dim3(512),  dim3(256), 0, stream, X, W, bias, degree8, Zd, Zsb, sinv);
  hipLaunchKernelGGL(k_main, dim3(512),  dim3(256), 0, stream, adjb, Zsb, P);
  hipLaunchKernelGGL(k_fin,  dim3(2048), dim3(256), 0, stream, P, Zd, sinv, out);
}

// Round 3
// 524.830 us; speedup vs baseline: 1.0087x; 1.0008x over previous
//
#include <hip/hip_runtime.h>

// GCN layer: out = ReLU( D^-1/2 (A+I) D^-1/2 X W + b ), N=8192, IN=OUT=256.
// fp32 I/O; bf16 internally for MFMA.
//   deg = rowsum(adj); s_i = rsqrt(deg_i+1); Z = X@W;
//   out[i,n] = relu( s_i * sum_j adj[i,j]*s_j*Z[j,n] + s_i^2*Z[i,n] + b[n] )
//
// v4: k_main rebuilt as a counted-vmcnt pipeline (T3/T4): BK=32, triple-buffer
// LDS (3 x 16512 B = 48 KB -> 3 blocks/CU, 12 waves/CU), ONE raw s_barrier per
// K-step, s_waitcnt vmcnt(4) (next tile's 4 GLDS stay in flight across the
// barrier -- never drain to 0 in the loop). k_deg/k_xw/k_fin unchanged from v3.
//
// adjb unit (16B = 8 bf16 along k) linear index (BYTE-IDENTICAL to v3's):
//   (mb2*4 + sk)*32768 + (k/8)-block*128 + r   [i32*512 + q*128 + r form]
// k_main LDS images per buffer: A stripe q at q*2064 (+r*16), B at 8256+q*2064.
// Zsb (bf16 s_k*Z[k][n]) 16B-unit idx = kt*2048 + kc*256 + n (unchanged).

typedef __attribute__((ext_vector_type(8))) short short8;
typedef __attribute__((ext_vector_type(4))) float floatx4;

#define GLDS16(g, l) __builtin_amdgcn_global_load_lds(\
    (const __attribute__((address_space(1))) void*)(g), \
    (__attribute__((address_space(3))) void*)(l), 16, 0, 0)

// fp32 -> bf16 round-to-nearest-even
__device__ __forceinline__ unsigned short f2b(float f) {
  unsigned int x = __builtin_bit_cast(unsigned int, f);
  unsigned int r = (x + 0x7fffu + ((x >> 16) & 1u)) >> 16;
  return (unsigned short)r;
}

// ---- kernel 1: adjb (bf16, k_main stream order) + 8 partial rowsums --------
// 512 blocks x 512 thr (2/CU). Block (mb2 = b>>3, sk = (b>>1)&3, h = b&1):
// rows mb2*128..+128, k-range sk*2048 + h*1024 ..+1024. Coalesced reads,
// XOR-swizzled LDS transpose, contiguous 16B-unit writes in k_main order.
__global__ __launch_bounds__(512) void k_deg(
    const float* __restrict__ adj, unsigned short* __restrict__ adjb,
    float* __restrict__ degree8) {
  __shared__ __align__(16) char xlds[65536];
  const int t = threadIdx.x, g = t >> 5, c = t & 31;
  const int mb2 = blockIdx.x >> 3, sk = (blockIdx.x >> 1) & 3, h = blockIdx.x & 1;
  const float* src = adj + (size_t)mb2 * 128 * 8192 + sk * 2048 + h * 1024;
  unsigned short* dstP = adjb
      + ((size_t)(mb2 * 4 + sk) * 32768 + (size_t)h * 16384) * 8;
  float rs[8] = {};
#pragma unroll
  for (int s = 0; s < 4; ++s) {
#pragma unroll
    for (int rr = 0; rr < 8; ++rr) {
      const int row = rr * 16 + g;
      const float* p = src + (size_t)row * 8192 + s * 256 + c * 8;
      float4 v0 = *(const float4*)(p);
      float4 v1 = *(const float4*)(p + 4);
      rs[rr] += ((v0.x + v0.y) + (v0.z + v0.w)) + ((v1.x + v1.y) + (v1.z + v1.w));
      short8 u;
      u[0] = f2b(v0.x); u[1] = f2b(v0.y); u[2] = f2b(v0.z); u[3] = f2b(v0.w);
      u[4] = f2b(v1.x); u[5] = f2b(v1.y); u[6] = f2b(v1.z); u[7] = f2b(v1.w);
      *(short8*)(xlds + c * 2048 + ((row ^ (c & 7)) * 16)) = u;
    }
    __syncthreads();
    unsigned short* dst = dstP + (size_t)s * 4096 * 8;
#pragma unroll
    for (int j = 0; j < 8; ++j) {
      const int lu = j * 512 + t;
      const int U = lu >> 7, R = lu & 127;
      short8 u = *(const short8*)(xlds + U * 2048 + ((R ^ (U & 7)) * 16));
      *(short8*)(dst + (size_t)lu * 8) = u;
    }
    __syncthreads();
  }
#pragma unroll
  for (int rr = 0; rr < 8; ++rr) {
#pragma unroll
    for (int o = 16; o > 0; o >>= 1) rs[rr] += __shfl_down(rs[rr], o, 32);
  }
  if (c == 0) {
    float* dp = degree8 + (size_t)(sk * 2 + h) * 8192 + mb2 * 128;
#pragma unroll
    for (int rr = 0; rr < 8; ++rr) dp[rr * 16 + g] = rs[rr];
  }
}

// ---- kernel 2: Z = X@W (VALU fp32); Zd = s^2 Z + b; Zsb swizzled; sinv ------
__global__ __launch_bounds__(256) void k_xw(
    const float* __restrict__ X, const float* __restrict__ W,
    const float* __restrict__ bias, const float* __restrict__ degree8,
    float* __restrict__ Zd, unsigned short* __restrict__ Zsb,
    float* __restrict__ sinv) {
  __shared__ unsigned short ldsT[256 * 20];   // [n][mm], stride 20 shorts
  const int t = threadIdx.x, l = t & 63, w = t >> 6;
  const int m0 = blockIdx.x * 16;
  const int r0 = w * 4;
  const int n0 = l * 4;
  const float* Xp = X + (size_t)(m0 + r0) * 256;
  float acc[4][4] = {};
#pragma unroll 2
  for (int k = 0; k < 256; k += 4) {
    float4 wv[4];
#pragma unroll
    for (int j = 0; j < 4; ++j) wv[j] = *(const float4*)(W + (size_t)(k + j) * 256 + n0);
#pragma unroll
    for (int r = 0; r < 4; ++r) {
      float4 xv = *(const float4*)(Xp + r * 256 + k);   // wave-uniform broadcast
      const float xs[4] = {xv.x, xv.y, xv.z, xv.w};
#pragma unroll
      for (int j = 0; j < 4; ++j) {
        acc[r][0] += xs[j] * wv[j].x;
        acc[r][1] += xs[j] * wv[j].y;
        acc[r][2] += xs[j] * wv[j].z;
        acc[r][3] += xs[j] * wv[j].w;
      }
    }
  }
  const float4 bv = *(const float4*)(bias + n0);
#pragma unroll
  for (int r = 0; r < 4; ++r) {
    const int row = m0 + r0 + r;
    float deg = 0.f;
#pragma unroll
    for (int p = 0; p < 8; ++p) deg += degree8[(size_t)p * 8192 + row];
    const float sr = rsqrtf(deg + 1.0f);
    if (l == 0) sinv[row] = sr;
    float4 zd;
    zd.x = sr * sr * acc[r][0] + bv.x;
    zd.y = sr * sr * acc[r][1] + bv.y;
    zd.z = sr * sr * acc[r][2] + bv.z;
    zd.w = sr * sr * acc[r][3] + bv.w;
    *(float4*)(Zd + (size_t)row * 256 + n0) = zd;
#pragma unroll
    for (int n = 0; n < 4; ++n)
      ldsT[(size_t)(n0 + n) * 20 + (r0 + r)] = f2b(sr * acc[r][n]);
  }
  __syncthreads();
  const int kt = m0 >> 6, kcb = (m0 >> 3) & 7;   // 16 rows = 2 kc groups
#pragma unroll
  for (int c = 0; c < 2; ++c) {
    const unsigned short* p = ldsT + (size_t)t * 20 + c * 8;
    short8 vv;
#pragma unroll
    for (int j = 0; j < 8; ++j) vv[j] = p[j];
    *(short8*)(Zsb + ((size_t)kt * 2048 + (kcb + c) * 256 + t) * 8) = vv;
  }
}

// ---- kernel 3: P[sk] = adjb @ Zsb, counted-vmcnt pipeline -------------------
// 512 blocks x 256 thr (3/CU, 12 waves/CU). b: bm2 = b>>3, bn = (b>>2)&1,
// sk = b&3. BM=128, BN=128, BK=32, 64 iters. Triple-buffer LDS; one raw
// s_barrier + s_waitcnt vmcnt(4) per iter (loads span barriers, never drain).
#define LDS_STG 16512   // A: 4*2064 = 8256 ; B: 4*2064 at +8256

#define STAGE_TILE(ib, s) do {                                               \
    char* bp_ = &lds[0][0] + (s) * LDS_STG;                                  \
    _Pragma("unroll")                                                        \
    for (int p_ = 0; p_ < 2; ++p_) {                                         \
      const int j_ = p_ * 256 + t;                                           \
      const int q_ = j_ >> 7, rr_ = j_ & 127;                                \
      GLDS16(aBase + ((size_t)(ib) * 512 + j_) * 8,                          \
             bp_ + q_ * 2064 + rr_ * 16);                                    \
      GLDS16(bBase + ((size_t)(ib) * 1024 + q_ * 256 + rr_) * 8,             \
             bp_ + 8256 + q_ * 2064 + rr_ * 16);                             \
    }                                                                        \
  } while (0)

#define K_COMPUTE(s) do {                                                    \
    const char* rA_ = &lds[0][0] + (s) * LDS_STG;                            \
    const char* rB_ = rA_ + 8256;                                            \
    short8 af_[4], bf_[4];                                                   \
    _Pragma("unroll")                                                        \
    for (int mi_ = 0; mi_ < 4; ++mi_)                                        \
      af_[mi_] = *(const short8*)(rA_ + quad * 2064 + (wm * 64 + mi_ * 16 + nl) * 16); \
    _Pragma("unroll")                                                        \
    for (int nf_ = 0; nf_ < 4; ++nf_)                                        \
      bf_[nf_] = *(const short8*)(rB_ + quad * 2064 + (wn * 64 + nf_ * 16 + nl) * 16); \
    __builtin_amdgcn_s_setprio(1);                                           \
    _Pragma("unroll")                                                        \
    for (int mi_ = 0; mi_ < 4; ++mi_)                                        \
      _Pragma("unroll")                                                      \
      for (int nf_ = 0; nf_ < 4; ++nf_)                                      \
        acc[mi_][nf_] = __builtin_amdgcn_mfma_f32_16x16x32_bf16(             \
            af_[mi_], bf_[nf_], acc[mi_][nf_], 0, 0, 0);                     \
    __builtin_amdgcn_s_setprio(0);                                           \
  } while (0)

#define VMW4 asm volatile("s_waitcnt vmcnt(4)" ::: "memory")
#define VMW0 asm volatile("s_waitcnt vmcnt(0)" ::: "memory")
#define RBAR do { __builtin_amdgcn_s_barrier();                              \
                  __builtin_amdgcn_sched_barrier(0); } while (0)

__global__ __launch_bounds__(256, 3) void k_main(
    const unsigned short* __restrict__ adjb, const unsigned short* __restrict__ Zsb,
    float* __restrict__ P) {
  __shared__ __align__(16) char lds[3][LDS_STG];   // 49536 B -> 3 blocks/CU
  const int t = threadIdx.x, l = t & 63, w = t >> 6;
  const int quad = l >> 4, nl = l & 15;
  const int bm2 = blockIdx.x >> 3, bn = (blockIdx.x >> 2) & 1, sk = blockIdx.x & 3;
  const int wm = w & 1, wn = w >> 1;             // 2x2 wave grid, 64x64 per wave
  const unsigned short* aBase = adjb + (size_t)(bm2 * 4 + sk) * 32768 * 8;
  const unsigned short* bBase = Zsb + ((size_t)sk * 65536 + bn * 128) * 8;
  floatx4 acc[4][4] = {};

  // prologue: tiles 0 and 1 in flight (8 outstanding GLDS per wave)
  STAGE_TILE(0, 0);
  STAGE_TILE(1, 1);

  int cur = 0;
  for (int i = 0; i < 62; ++i) {
    VMW4;                       // tile i landed; tile i+1's 4 stay in flight
    RBAR;
    const int nb = cur + 2 >= 3 ? cur - 1 : cur + 2;
    STAGE_TILE(i + 2, nb);      // issue-early: hides HBM latency under compute
    K_COMPUTE(cur);
    cur = cur + 1 == 3 ? 0 : cur + 1;
  }
  VMW4; RBAR; K_COMPUTE(cur);   // i = 62
  cur = cur + 1 == 3 ? 0 : cur + 1;
  VMW0; RBAR; K_COMPUTE(cur);   // i = 63 (full drain, last tile)

  float* Pk = P + (size_t)sk * 8192 * 256 + (size_t)bn * 128;
#pragma unroll
  for (int mi = 0; mi < 4; ++mi)
#pragma unroll
    for (int nf = 0; nf < 4; ++nf)
#pragma unroll
      for (int r = 0; r < 4; ++r) {
        const int row = bm2 * 128 + wm * 64 + mi * 16 + quad * 4 + r;
        const int col = wn * 64 + nf * 16 + nl;
        Pk[(size_t)row * 256 + col] = acc[mi][nf][r];
      }
}

// ---- kernel 4: out = relu( s_i*(P0+P1+P2+P3) + Zd ) ------------------------
__global__ __launch_bounds__(256) void k_fin(
    const float* __restrict__ P, const float* __restrict__ Zd,
    const float* __restrict__ sinv, float* __restrict__ out) {
  const int i = blockIdx.x * 256 + threadIdx.x;     // float4 index
  const int row = i >> 6;
  const float sr = sinv[row];
  const size_t stride = (size_t)8192 * 256;
  float4 p0 = *(const float4*)(P + (size_t)i * 4);
  float4 p1 = *(const float4*)(P + stride + (size_t)i * 4);
  float4 p2 = *(const float4*)(P + 2 * stride + (size_t)i * 4);
  float4 p3 = *(const float4*)(P + 3 * stride + (size_t)i * 4);
  const float4 zd = *(const float4*)(Zd + (size_t)i * 4);
  float4 v;
  v.x = sr * ((p0.x + p1.x) + (p2.x + p3.x)) + zd.x;
  v.y = sr * ((p0.y + p1.y) + (p2.y + p3.y)) + zd.y;
  v.z = sr * ((p0.z + p1.z) + (p2.z + p3.z)) + zd.z;
  v.w = sr * ((p0.w + p1.w) + (p2.w + p3.w)) + zd.w;
  v.x = v.x > 0.f ? v.x : 0.f;
  v.y = v.y > 0.f ? v.y : 0.f;
  v.z = v.z > 0.f ? v.z : 0.f;
  v.w = v.w > 0.f ? v.w : 0.f;
  *(float4*)(out + (size_t)i * 4) = v;
}

// ============================================================================
extern "C" void kernel_launch(void* const* d_in, const int* in_sizes, int n_in,
                              void* d_out, int out_size, void* d_ws, size_t ws_size,
                              hipStream_t stream) {
  const float* X    = (const float*)d_in[0];   // [8192][256]
  const float* adj  = (const float*)d_in[1];   // [8192][8192]
  const float* W    = (const float*)d_in[2];   // [256][256] ([in][out])
  const float* bias = (const float*)d_in[3];   // [256]
  float* out = (float*)d_out;                  // [8192][256]
  char* ws = (char*)d_ws;

  float* degree8       = (float*)(ws);                      // 256 KB (8 x 8192)
  float* sinv          = (float*)(ws + (512 << 10));        // 32 KB
  float* Zd            = (float*)(ws + (1 << 20));          // 8 MB
  unsigned short* Zsb  = (unsigned short*)(ws + (9 << 20)); // 4 MB
  float* P             = (float*)(ws + (13 << 20));         // 32 MB (4 x 8 MB)
  unsigned short* adjb = (unsigned short*)(ws + (45 << 20));// 128 MB -> total 173 MB

  hipLaunchKernelGGL(k_deg,  dim3(512),  dim3(512), 0, stream, adj, adjb, degree8);
  hipLaunchKernelGGL(k_xw,   dim3(512),  dim3(256), 0, stream, X, W, bias, degree8, Zd, Zsb, sinv);
  hipLaunchKernelGGL(k_main, dim3(512),  dim3(256), 0, stream, adjb, Zsb, P);
  hipLaunchKernelGGL(k_fin,  dim3(2048), dim3(256), 0, stream, P, Zd, sinv, out);
}

// Round 5
// 517.627 us; speedup vs baseline: 1.0227x; 1.0139x over previous
//
#include <hip/hip_runtime.h>

// GCN layer: out = ReLU( D^-1/2 (A+I) D^-1/2 X W + b ), N=8192, IN=OUT=256.
// fp32 I/O; bf16 internally for MFMA.
//   deg = rowsum(adj); s_i = rsqrt(deg_i+1); Z = X@W;
//   out[i,n] = relu( s_i * sum_j adj[i,j]*s_j*Z[j,n] + s_i^2*Z[i,n] + b[n] )
//
// v5b = v5 with __launch_bounds__(512) (no min-occupancy clamp; suspected
// compile-kill in v5). Structure: R0's measured-best byte layout (no adjb;
// k_main reads fp32 adj, converts in-register) + counted-vmcnt single-barrier
// pipeline (B GLDS + A glb loads stay in flight across the barrier; never
// vmcnt(0) in the loop) + lean k_deg emitting sinv directly.
//
// Zsb (bf16 s_k*Z[k][n]) 16B-unit idx = kt*2048 + kc*256 + n
//   (kt = k/64, kc = (k/8)&7; per BK=32 tile i of sk-slab: units
//    sk*65536 + i*1024 + (cq*256 + n), cq = (k%32)/8)

typedef __attribute__((ext_vector_type(8))) short short8;
typedef __attribute__((ext_vector_type(4))) float floatx4;

#define GLDS16(g, l) __builtin_amdgcn_global_load_lds(\
    (const __attribute__((address_space(1))) void*)(g), \
    (__attribute__((address_space(3))) void*)(l), 16, 0, 0)

#define VMW1  asm volatile("s_waitcnt vmcnt(1)" ::: "memory")
#define VMW3  asm volatile("s_waitcnt vmcnt(3)" ::: "memory")
#define VMW0  asm volatile("s_waitcnt vmcnt(0)" ::: "memory")
#define LGKM0 asm volatile("s_waitcnt lgkmcnt(0)" ::: "memory")

// fp32 -> bf16 round-to-nearest-even
__device__ __forceinline__ unsigned short f2b(float f) {
  unsigned int x = __builtin_bit_cast(unsigned int, f);
  unsigned int r = (x + 0x7fffu + ((x >> 16) & 1u)) >> 16;
  return (unsigned short)r;
}

// ---- kernel 1: rowsum(adj) -> sinv -----------------------------------------
// 1024 blocks x 256 thr (4/CU). Row-subgroup = 32 lanes, 512B contiguous per
// row per iter. No LDS, no atomics, no barriers.
__global__ __launch_bounds__(256) void k_deg(
    const float* __restrict__ adj, float* __restrict__ sinv) {
  const int t = threadIdx.x;
  const int row = blockIdx.x * 8 + (t >> 5);
  const int c = t & 31;
  const float* src = adj + (size_t)row * 8192 + c * 4;
  float rs = 0.f;
#pragma unroll 8
  for (int it = 0; it < 64; ++it) {
    float4 v = *(const float4*)(src + it * 128);
    rs += v.x + v.y + v.z + v.w;
  }
#pragma unroll
  for (int o = 16; o > 0; o >>= 1) rs += __shfl_down(rs, o, 32);
  if (c == 0) sinv[row] = rsqrtf(rs + 1.0f);
}

// ---- kernel 2: Z = X@W (VALU fp32); Zd = s^2 Z + b; Zsb swizzled ------------
// 512 blocks x 256 thr. Wave w: rows m0+4w..+4; lane l: cols 4l..4l+4.
__global__ __launch_bounds__(256) void k_xw(
    const float* __restrict__ X, const float* __restrict__ W,
    const float* __restrict__ bias, const float* __restrict__ sinv,
    float* __restrict__ Zd, unsigned short* __restrict__ Zsb) {
  __shared__ unsigned short ldsT[256 * 20];   // [n][mm], stride 20 shorts
  const int t = threadIdx.x, l = t & 63, w = t >> 6;
  const int m0 = blockIdx.x * 16;
  const int r0 = w * 4;
  const int n0 = l * 4;
  const float* Xp = X + (size_t)(m0 + r0) * 256;
  float acc[4][4] = {};
#pragma unroll 2
  for (int k = 0; k < 256; k += 4) {
    float4 wv[4];
#pragma unroll
    for (int j = 0; j < 4; ++j) wv[j] = *(const float4*)(W + (size_t)(k + j) * 256 + n0);
#pragma unroll
    for (int r = 0; r < 4; ++r) {
      float4 xv = *(const float4*)(Xp + r * 256 + k);   // wave-uniform broadcast
      const float xs[4] = {xv.x, xv.y, xv.z, xv.w};
#pragma unroll
      for (int j = 0; j < 4; ++j) {
        acc[r][0] += xs[j] * wv[j].x;
        acc[r][1] += xs[j] * wv[j].y;
        acc[r][2] += xs[j] * wv[j].z;
        acc[r][3] += xs[j] * wv[j].w;
      }
    }
  }
  const float4 bv = *(const float4*)(bias + n0);
#pragma unroll
  for (int r = 0; r < 4; ++r) {
    const int row = m0 + r0 + r;
    const float sr = sinv[row];
    float4 zd;
    zd.x = sr * sr * acc[r][0] + bv.x;
    zd.y = sr * sr * acc[r][1] + bv.y;
    zd.z = sr * sr * acc[r][2] + bv.z;
    zd.w = sr * sr * acc[r][3] + bv.w;
    *(float4*)(Zd + (size_t)row * 256 + n0) = zd;
#pragma unroll
    for (int n = 0; n < 4; ++n)
      ldsT[(size_t)(n0 + n) * 20 + (r0 + r)] = f2b(sr * acc[r][n]);
  }
  __syncthreads();
  const int kt = m0 >> 6, kcb = (m0 >> 3) & 7;   // 16 rows = 2 kc groups
#pragma unroll
  for (int c = 0; c < 2; ++c) {
    const unsigned short* p = ldsT + (size_t)t * 20 + c * 8;
    short8 vv;
#pragma unroll
    for (int j = 0; j < 8; ++j) vv[j] = p[j];
    *(short8*)(Zsb + ((size_t)kt * 2048 + (kcb + c) * 256 + t) * 8) = vv;
  }
}

// ---- kernel 3: P[sk] = adj(fp32,cvt) @ Zsb, split-K=4, counted pipeline -----
// 512 blocks x 512 thr (2/CU, 16 waves/CU). b: bm = b>>2, sk = b&3.
// BM=64, BN=256, BK=32, 64 iters. Per iter: VMW(1)+lgkm0+raw barrier (B and A
// prefetch loads stay in flight across the barrier), stage B(i+1) GLDS +
// A(i+2) glb->reg, VMW(3) -> pack A(i+1) -> ds_write, 6 ds_read + 8 MFMA.
__global__ __launch_bounds__(512) void k_main(
    const float* __restrict__ adj, const unsigned short* __restrict__ Zsb,
    float* __restrict__ P) {
  // per stage: A = 4*1040 = 4160 (pad to 4224, 16-al), B = 16384 -> 20608
  __shared__ __align__(16) char lds[2][20608];
  const int t = threadIdx.x, l = t & 63, w = t >> 6;
  const int quad = l >> 4, nl = l & 15;
  const int bm = blockIdx.x >> 2, sk = blockIdx.x & 3;
  const int m0 = bm * 64;
  const int wm = w & 1, wn = w >> 1;           // 2x4 wave grid, 32x64 per wave
  const int aRow = t >> 3, aCol = t & 7;
  const float* aSrc = adj + (size_t)(m0 + aRow) * 8192 + sk * 2048 + aCol * 4;
  const int aOff = (aCol >> 1) * 1040 + aRow * 16 + (aCol & 1) * 8;
  const unsigned short* bBase = Zsb + (size_t)sk * 65536 * 8;
  floatx4 acc[2][4] = {};

  // prologue: B(0) staged; A(0),A(1) in flight; A(0) packed into lds[0]
#pragma unroll
  for (int q = 0; q < 2; ++q) {
    const int sl = q * 512 + t;
    GLDS16(bBase + (size_t)sl * 8, lds[0] + 4224 + sl * 16);
  }
  float4 avP = *(const float4*)(aSrc);
  float4 avN = *(const float4*)(aSrc + 32);
  {
    // compiler-inserted wait for avP drains B(0) too (prologue only)
    unsigned short u0 = f2b(avP.x), u1 = f2b(avP.y), u2 = f2b(avP.z), u3 = f2b(avP.w);
    unsigned long long pk = (unsigned long long)u0 | ((unsigned long long)u1 << 16)
                          | ((unsigned long long)u2 << 32) | ((unsigned long long)u3 << 48);
    *(unsigned long long*)(lds[0] + aOff) = pk;
  }
  avP = avN;

#pragma unroll 2
  for (int i = 0; i < 64; ++i) {
    const int cur = i & 1, nxt = cur ^ 1;
    const int ib = i < 63 ? i + 1 : 63;        // B tile to stage (clamped ok)
    const int ia = i < 62 ? i + 2 : 63;        // A tile to fetch  (clamped ok)
    VMW1;                                      // my B(i) landed; A(i+1) in flight
    LGKM0;                                     // my A(i) ds_write committed
    __builtin_amdgcn_s_barrier();
    __builtin_amdgcn_sched_barrier(0);
    // stage into nxt: B(i+1) via GLDS, A(i+2) into regs — span the next barrier
#pragma unroll
    for (int q = 0; q < 2; ++q) {
      const int sl = q * 512 + t;
      GLDS16(bBase + (size_t)(ib * 1024 + sl) * 8, lds[nxt] + 4224 + sl * 16);
    }
    avN = *(const float4*)(aSrc + ia * 32);
    VMW3;                                      // A(i+1) landed; 3 newest in flight
    __builtin_amdgcn_sched_barrier(0);
    {
      unsigned short u0 = f2b(avP.x), u1 = f2b(avP.y), u2 = f2b(avP.z), u3 = f2b(avP.w);
      unsigned long long pk = (unsigned long long)u0 | ((unsigned long long)u1 << 16)
                            | ((unsigned long long)u2 << 32) | ((unsigned long long)u3 << 48);
      *(unsigned long long*)(lds[nxt] + aOff) = pk;
    }
    avP = avN;
    // compute tile i from cur
    const char* rA = lds[cur];
    const char* rB = lds[cur] + 4224;
    short8 af[2], bf[4];
    af[0] = *(const short8*)(rA + quad * 1040 + (wm * 32 + nl) * 16);
    af[1] = *(const short8*)(rA + quad * 1040 + (wm * 32 + 16 + nl) * 16);
#pragma unroll
    for (int nf = 0; nf < 4; ++nf) {
      const int col = wn * 64 + nf * 16 + nl;
      bf[nf] = *(const short8*)(rB + ((size_t)quad * 256 + col) * 16);
    }
    __builtin_amdgcn_s_setprio(1);
#pragma unroll
    for (int mi = 0; mi < 2; ++mi)
#pragma unroll
      for (int nf = 0; nf < 4; ++nf)
        acc[mi][nf] = __builtin_amdgcn_mfma_f32_16x16x32_bf16(af[mi], bf[nf], acc[mi][nf], 0, 0, 0);
    __builtin_amdgcn_s_setprio(0);
  }
  VMW0;   // hygiene: drain leftover redundant prefetches before epilogue

  float* Pk = P + (size_t)sk * 8192 * 256;
#pragma unroll
  for (int mi = 0; mi < 2; ++mi)
#pragma unroll
    for (int nf = 0; nf < 4; ++nf)
#pragma unroll
      for (int r = 0; r < 4; ++r) {
        const int row = m0 + wm * 32 + mi * 16 + quad * 4 + r;
        const int col = wn * 64 + nf * 16 + nl;
        Pk[(size_t)row * 256 + col] = acc[mi][nf][r];
      }
}

// ---- kernel 4: out = relu( s_i*(P0+P1+P2+P3) + Zd ) ------------------------
__global__ __launch_bounds__(256) void k_fin(
    const float* __restrict__ P, const float* __restrict__ Zd,
    const float* __restrict__ sinv, float* __restrict__ out) {
  const int i = blockIdx.x * 256 + threadIdx.x;     // float4 index
  const int row = i >> 6;
  const float sr = sinv[row];
  const size_t stride = (size_t)8192 * 256;
  float4 p0 = *(const float4*)(P + (size_t)i * 4);
  float4 p1 = *(const float4*)(P + stride + (size_t)i * 4);
  float4 p2 = *(const float4*)(P + 2 * stride + (size_t)i * 4);
  float4 p3 = *(const float4*)(P + 3 * stride + (size_t)i * 4);
  const float4 zd = *(const float4*)(Zd + (size_t)i * 4);
  float4 v;
  v.x = sr * ((p0.x + p1.x) + (p2.x + p3.x)) + zd.x;
  v.y = sr * ((p0.y + p1.y) + (p2.y + p3.y)) + zd.y;
  v.z = sr * ((p0.z + p1.z) + (p2.z + p3.z)) + zd.z;
  v.w = sr * ((p0.w + p1.w) + (p2.w + p3.w)) + zd.w;
  v.x = v.x > 0.f ? v.x : 0.f;
  v.y = v.y > 0.f ? v.y : 0.f;
  v.z = v.z > 0.f ? v.z : 0.f;
  v.w = v.w > 0.f ? v.w : 0.f;
  *(float4*)(out + (size_t)i * 4) = v;
}

// ============================================================================
extern "C" void kernel_launch(void* const* d_in, const int* in_sizes, int n_in,
                              void* d_out, int out_size, void* d_ws, size_t ws_size,
                              hipStream_t stream) {
  const float* X    = (const float*)d_in[0];   // [8192][256]
  const float* adj  = (const float*)d_in[1];   // [8192][8192]
  const float* W    = (const float*)d_in[2];   // [256][256] ([in][out])
  const float* bias = (const float*)d_in[3];   // [256]
  float* out = (float*)d_out;                  // [8192][256]
  char* ws = (char*)d_ws;

  float* sinv          = (float*)(ws);                      // 32 KB
  float* Zd            = (float*)(ws + (1 << 20));          // 8 MB
  unsigned short* Zsb  = (unsigned short*)(ws + (9 << 20)); // 4 MB
  float* P             = (float*)(ws + (13 << 20));         // 32 MB (4 x 8 MB)

  hipLaunchKernelGGL(k_deg,  dim3(1024), dim3(256), 0, stream, adj, sinv);
  hipLaunchKernelGGL(k_xw,   dim3(512),  dim3(256), 0, stream, X, W, bias, sinv, Zd, Zsb);
  hipLaunchKernelGGL(k_main, dim3(512),  dim3(512), 0, stream, adj, Zsb, P);
  hipLaunchKernelGGL(k_fin,  dim3(2048), dim3(256), 0, stream, P, Zd, sinv, out);
}